// Round 16
// baseline (97.006 us; speedup 1.0000x reference)
//
#include <hip/hip_runtime.h>
#include <hip/hip_bf16.h>

static constexpr int B_ = 16, T_ = 512, E_ = 512, H_ = 8, HD_ = 64;
static constexpr int S2_ = 1023, BH_ = B_ * H_;

typedef __attribute__((ext_vector_type(4))) float f32x4;
typedef __attribute__((ext_vector_type(8))) short bf16x8;

__device__ __forceinline__ unsigned short f2b(float f) {
    union { float f; unsigned u; } v; v.f = f;
    unsigned r = (v.u + 0x7fff + ((v.u >> 16) & 1)) >> 16;
    return (unsigned short)r;
}
__device__ __forceinline__ unsigned int pk2(float a, float b) {
    __hip_bfloat162 h = __float22bfloat162_rn(float2{a, b});
    union { __hip_bfloat162 h; unsigned int u; } c; c.h = h; return c.u;
}
__device__ __forceinline__ void gll16(const unsigned short* g, unsigned short* l) {
    __builtin_amdgcn_global_load_lds((const __attribute__((address_space(1))) unsigned int*)g,
                                     (__attribute__((address_space(3))) unsigned int*)l, 16, 0, 0);
}

// fp32 -> bf16 convert of x, pos_emb, Wq,Wk,Wv,Wp ; tail blocks zero p row 1023.
static constexpr long NX_ = 4194304;        // 16*512*512
static constexpr long NPE_ = 8380416;       // 16*1023*512
static constexpr long NW_ = 262144;         // 512*512
static constexpr long TOT_ = NX_ + NPE_ + 4 * NW_;   // 13623296
__global__ __launch_bounds__(256)
void convert_bf16(const float* __restrict__ x, const float* __restrict__ pe,
                  const float* __restrict__ wq, const float* __restrict__ wk,
                  const float* __restrict__ wv, const float* __restrict__ wp,
                  unsigned short* __restrict__ xb, unsigned short* __restrict__ pb,
                  unsigned short* __restrict__ wb, unsigned short* __restrict__ p)
{
    long i8 = ((long)blockIdx.x * 256 + threadIdx.x) * 8;
    if (i8 >= TOT_) {
        long idx8 = i8 - TOT_;                 // [0, 8192)
        int bh = (int)(idx8 >> 6), d = (int)(idx8 & 63);
        bf16x8 z = {};
        *reinterpret_cast<bf16x8*>(&p[((long)bh * 1024 + 1023) * 64 + d]) = z;
        return;
    }
    const float* src;
    unsigned short* dst;
    if (i8 < NX_) { src = x + i8; dst = xb + i8; }
    else if (i8 < NX_ + NPE_) { long o = i8 - NX_; src = pe + o; dst = pb + o; }
    else {
        long w = i8 - (NX_ + NPE_);
        int which = (int)(w >> 18);
        long off = w & (NW_ - 1);
        src = (which == 0 ? wq : which == 1 ? wk : which == 2 ? wv : wp) + off;
        dst = wb + ((long)which << 18) + off;
    }
    float4 a = *reinterpret_cast<const float4*>(src);
    float4 b = *reinterpret_cast<const float4*>(src + 4);
    union { bf16x8 v; unsigned int u[4]; } r;
    r.u[0] = pk2(a.x, a.y); r.u[1] = pk2(a.z, a.w);
    r.u[2] = pk2(b.x, b.y); r.u[3] = pk2(b.z, b.w);
    *reinterpret_cast<bf16x8*>(dst) = r.v;
}

// Unified projection GEMM (r10-proven): double-buffered gll16 staging, counted
// vmcnt, XOR-swizzled linear LDS, LDS-staged coalesced bf16x8 epilogue.
// blocks 0..767: QKV (mode 0/1/2), blocks 768..1279: P (mode 3).
// qu/qv carry 0.125*log2(e) so attention softmax can use native exp2.
__global__ __launch_bounds__(256)
void proj_all(const unsigned short* __restrict__ xb, const unsigned short* __restrict__ pb,
              const unsigned short* __restrict__ wb,
              const float* __restrict__ bq, const float* __restrict__ bk,
              const float* __restrict__ bv,
              const float* __restrict__ pbu, const float* __restrict__ pbv,
              unsigned short* __restrict__ qu, unsigned short* __restrict__ qv,
              unsigned short* __restrict__ kk, unsigned short* __restrict__ vT,
              unsigned short* __restrict__ pout)
{
    __shared__ __align__(16) unsigned short LDS[2][2][8192];   // [buf][A/W][128*64]
    const int tid = threadIdx.x;
    const int lane = tid & 63, w = tid >> 6;
    const int wr = w >> 1, wc = w & 1;
    const int g = lane >> 4, li = lane & 15;
    const int lr = lane >> 3;
    const int lcs = (((lane & 7) ^ (lane >> 3)) * 8);   // pre-swizzled source col

    int mode, m0, n0, M;
    const unsigned short* Ap;
    const float* bias = nullptr;
    if (blockIdx.x < 768) {
        int n = blockIdx.x;
        int xcd = n & 7, s = n >> 3;
        int gi = s / 12, c = s % 12;
        m0 = (gi * 8 + xcd) * 128;
        mode = c >> 2; n0 = (c & 3) * 128;
        Ap = xb; M = 8192;
        bias = (mode == 0) ? bq : (mode == 1) ? bk : bv;
    } else {
        int n = blockIdx.x - 768;
        int xcd = n & 7, s = n >> 3;
        int gi = s >> 2, c = s & 3;
        m0 = (gi * 8 + xcd) * 128;
        mode = 3; n0 = c * 128;
        Ap = pb; M = B_ * S2_;
    }
    const unsigned short* W = wb + ((long)mode << 18);

    auto stage = [&](int buf, int k0) {
#pragma unroll
        for (int i = 0; i < 4; ++i) {
            int c = w * 4 + i;
            int ar = m0 + c * 8 + lr; if (ar > M - 1) ar = M - 1;
            gll16(&Ap[(long)ar * 512 + k0 + lcs], &LDS[buf][0][c * 512]);
            gll16(&W[(long)(n0 + c * 8 + lr) * 512 + k0 + lcs], &LDS[buf][1][c * 512]);
        }
    };

    f32x4 acc[4][4] = {};
    stage(0, 0);
    for (int s = 0; s < 8; ++s) {
        if (s < 7) stage((s + 1) & 1, (s + 1) * 64);
        __builtin_amdgcn_sched_barrier(0);
        if (s < 7) { asm volatile("s_waitcnt vmcnt(8)" ::: "memory"); }
        else       { asm volatile("s_waitcnt vmcnt(0)" ::: "memory"); }
        __builtin_amdgcn_sched_barrier(0);
        __builtin_amdgcn_s_barrier();
        __builtin_amdgcn_sched_barrier(0);   // ds_reads must stay AFTER the barrier
        const unsigned short* As = &LDS[s & 1][0][0];
        const unsigned short* Ws = &LDS[s & 1][1][0];
#pragma unroll
        for (int ks = 0; ks < 2; ++ks) {
            bf16x8 a[4], b[4];
            const int colsw = (ks * 32 + g * 8) ^ ((li & 7) << 3);
#pragma unroll
            for (int m = 0; m < 4; ++m)
                a[m] = *reinterpret_cast<const bf16x8*>(&As[(wr * 64 + m * 16 + li) * 64 + colsw]);
#pragma unroll
            for (int nn = 0; nn < 4; ++nn)
                b[nn] = *reinterpret_cast<const bf16x8*>(&Ws[(wc * 64 + nn * 16 + li) * 64 + colsw]);
            __builtin_amdgcn_s_setprio(1);
#pragma unroll
            for (int m = 0; m < 4; ++m)
#pragma unroll
                for (int nn = 0; nn < 4; ++nn)
                    acc[m][nn] = __builtin_amdgcn_mfma_f32_16x16x32_bf16(a[m], b[nn], acc[m][nn], 0, 0, 0);
            __builtin_amdgcn_s_setprio(0);
        }
        __builtin_amdgcn_sched_barrier(0);
        __builtin_amdgcn_s_barrier();
        __builtin_amdgcn_sched_barrier(0);
    }

    // Epilogue scalars (after vmcnt(0); compiler-managed waits)
    float bias_[4] = {0.f, 0.f, 0.f, 0.f}, pu_[4] = {0.f, 0.f, 0.f, 0.f}, pv_[4] = {0.f, 0.f, 0.f, 0.f};
    if (mode != 3) {
#pragma unroll
        for (int nn = 0; nn < 4; ++nn) {
            int gn = n0 + wc * 64 + nn * 16 + li;
            bias_[nn] = bias[gn];
            if (mode == 0) { pu_[nn] = pbu[gn]; pv_[nn] = pbv[gn]; }
        }
    }

    // ---- LDS-staged coalesced epilogue: Ct is a [128][136] bf16 tile ----
    unsigned short* Ct = &LDS[0][0][0];
    const int rrow = tid >> 4, rcol = (tid & 15) * 8;
    const float QS = 0.125f * 1.4426950408889634f;   // 1/8 * log2(e)

    if (mode == 2) {
#pragma unroll
        for (int m = 0; m < 4; ++m)
#pragma unroll
            for (int nn = 0; nn < 4; ++nn) {
                ushort4 pk;
                pk.x = f2b(acc[m][nn][0] + bias_[nn]);
                pk.y = f2b(acc[m][nn][1] + bias_[nn]);
                pk.z = f2b(acc[m][nn][2] + bias_[nn]);
                pk.w = f2b(acc[m][nn][3] + bias_[nn]);
                *reinterpret_cast<ushort4*>(&Ct[(wc * 64 + nn * 16 + li) * 136 + wr * 64 + m * 16 + g * 4]) = pk;
            }
        __syncthreads();
#pragma unroll
        for (int ps = 0; ps < 8; ++ps) {
            int rowd = ps * 16 + rrow;
            int gn = n0 + rowd, gm = m0 + rcol;
            int hh = gn >> 6, d = gn & 63, bb = gm >> 9, t = gm & 511;
            *reinterpret_cast<bf16x8*>(&vT[((long)(bb * 8 + hh) * 64 + d) * 512 + t]) =
                *reinterpret_cast<const bf16x8*>(&Ct[rowd * 136 + rcol]);
        }
    } else if (mode != 0) {
#pragma unroll
        for (int m = 0; m < 4; ++m)
#pragma unroll
            for (int nn = 0; nn < 4; ++nn)
#pragma unroll
                for (int r = 0; r < 4; ++r)
                    Ct[(wr * 64 + m * 16 + g * 4 + r) * 136 + wc * 64 + nn * 16 + li] =
                        f2b(acc[m][nn][r] + bias_[nn]);
        __syncthreads();
#pragma unroll
        for (int ps = 0; ps < 8; ++ps) {
            int row = ps * 16 + rrow;
            int gm = m0 + row, gn = n0 + rcol;
            bf16x8 v = *reinterpret_cast<const bf16x8*>(&Ct[row * 136 + rcol]);
            if (mode == 1) {
                int bb = gm >> 9, t = gm & 511, hh = gn >> 6, d = gn & 63;
                *reinterpret_cast<bf16x8*>(&kk[((long)(bb * 8 + hh) * 512 + t) * 64 + d]) = v;
            } else if (gm < M) {
                int bb = gm / 1023, j = gm - bb * 1023;
                int hh = gn >> 6, d = gn & 63;
                *reinterpret_cast<bf16x8*>(&pout[((long)(bb * 8 + hh) * 1024 + j) * 64 + d]) = v;
            }
        }
    } else {
#pragma unroll
        for (int m = 0; m < 4; ++m)
#pragma unroll
            for (int nn = 0; nn < 4; ++nn)
#pragma unroll
                for (int r = 0; r < 4; ++r)
                    Ct[(wr * 64 + m * 16 + g * 4 + r) * 136 + wc * 64 + nn * 16 + li] =
                        f2b((acc[m][nn][r] + bias_[nn] + pu_[nn]) * QS);
        __syncthreads();
#pragma unroll
        for (int ps = 0; ps < 8; ++ps) {
            int row = ps * 16 + rrow;
            int gm = m0 + row, gn = n0 + rcol;
            int bb = gm >> 9, t = gm & 511, hh = gn >> 6, d = gn & 63;
            *reinterpret_cast<bf16x8*>(&qu[((long)(bb * 8 + hh) * 512 + t) * 64 + d]) =
                *reinterpret_cast<const bf16x8*>(&Ct[row * 136 + rcol]);
        }
        __syncthreads();
#pragma unroll
        for (int m = 0; m < 4; ++m)
#pragma unroll
            for (int nn = 0; nn < 4; ++nn)
#pragma unroll
                for (int r = 0; r < 4; ++r)
                    Ct[(wr * 64 + m * 16 + g * 4 + r) * 136 + wc * 64 + nn * 16 + li] =
                        f2b((acc[m][nn][r] + bias_[nn] + pv_[nn]) * QS);
        __syncthreads();
#pragma unroll
        for (int ps = 0; ps < 8; ++ps) {
            int row = ps * 16 + rrow;
            int gm = m0 + row, gn = n0 + rcol;
            int bb = gm >> 9, t = gm & 511, hh = gn >> 6, d = gn & 63;
            *reinterpret_cast<bf16x8*>(&qv[((long)(bb * 8 + hh) * 512 + t) * 64 + d]) =
                *reinterpret_cast<const bf16x8*>(&Ct[row * 136 + rcol]);
        }
    }
}

// Fused attention v8: QBLK=128, 4 waves x 32 q-rows (two 16-row groups per
// wave). Every K/p/V B-fragment read feeds TWO MFMAs; the rowgroups' BD
// windows overlap by 64 so 6 shared p-frags serve both (12 reads vs 20).
// Same circular-Pw single-barrier pipeline, swizzles, shfl gather, exp2
// softmax, deferred sum as v7.
__global__ __launch_bounds__(256)
void attn_fused(const unsigned short* __restrict__ qu, const unsigned short* __restrict__ qv,
                const unsigned short* __restrict__ kk, const unsigned short* __restrict__ vT,
                const unsigned short* __restrict__ p, float* __restrict__ out)
{
    __shared__ unsigned short Ks[2][64][64];   // XOR-swizzled: col ^ ((row&7)<<3)
    __shared__ unsigned short Vs[2][64][64];
    __shared__ unsigned short Pw[256][64];     // circular window, row = global&255
    __shared__ unsigned short UN[4][2][16][64];
    const int tid = threadIdx.x, lane = tid & 63, w = tid >> 6;   // w 0..3
    const int g = lane >> 4, li = lane & 15;
    const int n = blockIdx.x;            // 0..511, XCD-swizzled
    const int xcd = n & 7, rr = n >> 3;
    const int j = rr & 15, ti = rr >> 4; // ti 0..3
    const int bh = xcd * 16 + j;
    const int bb = bh >> 3, hh = bh & 7;
    const int t0 = ti * 128;
    const int wo1 = 96 - w * 32;         // rowgroup1 window offset (rg0 = wo1+16)
    const int base0 = 384 - t0;          // p-window base row for s0=0

    bf16x8 aq0[2], av0[2], aq1[2], av1[2];
    {
        const int tr0 = t0 + (w * 2) * 16 + li;
#pragma unroll
        for (int ks = 0; ks < 2; ++ks) {
            aq0[ks] = *reinterpret_cast<const bf16x8*>(&qu[((long)bh * 512 + tr0) * 64 + ks * 32 + g * 8]);
            av0[ks] = *reinterpret_cast<const bf16x8*>(&qv[((long)bh * 512 + tr0) * 64 + ks * 32 + g * 8]);
            aq1[ks] = *reinterpret_cast<const bf16x8*>(&qu[((long)bh * 512 + tr0 + 16) * 64 + ks * 32 + g * 8]);
            av1[ks] = *reinterpret_cast<const bf16x8*>(&qv[((long)bh * 512 + tr0 + 16) * 64 + ks * 32 + g * 8]);
        }
    }

    const int srow = tid >> 3, scol8 = (tid & 7) * 8;    // 32 rows x 8 vec-cols
    const int scolsw = scol8 ^ ((srow & 7) << 3);        // row+32 keeps row&7

    // prologue: tile-0 K/V and the initial 192-row p window
    {
#pragma unroll
        for (int i = 0; i < 2; ++i) {
            int row = srow + i * 32;
            *reinterpret_cast<bf16x8*>(&Ks[0][row][scolsw]) =
                *reinterpret_cast<const bf16x8*>(&kk[((long)bh * 512 + row) * 64 + scol8]);
            *reinterpret_cast<bf16x8*>(&Vs[0][row][scolsw]) =
                *reinterpret_cast<const bf16x8*>(&vT[((long)bh * 64 + row) * 512 + scol8]);
        }
#pragma unroll
        for (int i = 0; i < 6; ++i) {
            int pr = base0 + srow + i * 32;
            *reinterpret_cast<bf16x8*>(&Pw[pr & 255][scolsw]) =
                *reinterpret_cast<const bf16x8*>(&p[((long)bh * 1024 + pr) * 64 + scol8]);
        }
    }
    __syncthreads();

    f32x4 O0[4] = {}, O1[4] = {};
    float lrow0[4] = {0.f, 0.f, 0.f, 0.f}, lrow1[4] = {0.f, 0.f, 0.f, 0.f};
    bf16x8 kreg[2], vreg[2], preg[2];
    int cur = 0;

    for (int it = 0; it < 8; ++it) {
        const int s0 = it * 64;
        if (it < 7) {      // issue next-tile loads early (hide under compute)
#pragma unroll
            for (int i = 0; i < 2; ++i) {
                int row = srow + i * 32;
                kreg[i] = *reinterpret_cast<const bf16x8*>(&kk[((long)bh * 512 + s0 + 64 + row) * 64 + scol8]);
                vreg[i] = *reinterpret_cast<const bf16x8*>(&vT[((long)bh * 64 + row) * 512 + s0 + 64 + scol8]);
                preg[i] = *reinterpret_cast<const bf16x8*>(&p[((long)bh * 1024 + base0 + s0 + 192 + row) * 64 + scol8]);
            }
        }
        // QK^T + BD, B-fragments shared across both rowgroups
        f32x4 S0[4] = {}, S1[4] = {};
        f32x4 bd0[5] = {}, bd1[5] = {};
        __builtin_amdgcn_s_setprio(1);
#pragma unroll
        for (int ks = 0; ks < 2; ++ks) {
            const int colsw = (ks * 32 + g * 8) ^ ((li & 7) << 3);
#pragma unroll
            for (int f = 0; f < 4; ++f) {
                bf16x8 bf = *reinterpret_cast<const bf16x8*>(&Ks[cur][f * 16 + li][colsw]);
                S0[f] = __builtin_amdgcn_mfma_f32_16x16x32_bf16(aq0[ks], bf, S0[f], 0, 0, 0);
                S1[f] = __builtin_amdgcn_mfma_f32_16x16x32_bf16(aq1[ks], bf, S1[f], 0, 0, 0);
            }
#pragma unroll
            for (int q = 0; q < 6; ++q) {
                int prow = (base0 + s0 + wo1 + q * 16 + li) & 255;
                bf16x8 bf = *reinterpret_cast<const bf16x8*>(&Pw[prow][colsw]);
                if (q < 5) bd1[q] = __builtin_amdgcn_mfma_f32_16x16x32_bf16(av1[ks], bf, bd1[q], 0, 0, 0);
                if (q > 0) bd0[q - 1] = __builtin_amdgcn_mfma_f32_16x16x32_bf16(av0[ks], bf, bd0[q - 1], 0, 0, 0);
            }
        }
        __builtin_amdgcn_s_setprio(0);
        // per-rowgroup: diagonal gather + exp2 + partial sums + UN write
        auto smax = [&](f32x4 (&S)[4], f32x4 (&bd)[5], float (&lr)[4], int h) {
#pragma unroll
            for (int r = 0; r < 4; ++r) {
                const int tt = g * 4 + r;
                const int sh = 15 - tt;
                const int srcl = (lane & 48) | ((li + sh) & 15);
                const bool wrap = (li + sh) >= 16;
                float sv[5];
#pragma unroll
                for (int q = 0; q < 5; ++q) sv[q] = __shfl(bd[q][r], srcl, 64);
#pragma unroll
                for (int f = 0; f < 4; ++f) {
                    float pv = __builtin_exp2f(S[f][r] + (wrap ? sv[f + 1] : sv[f]));
                    S[f][r] = pv;
                    lr[r] += pv;
                }
            }
#pragma unroll
            for (int f = 0; f < 4; ++f)
#pragma unroll
                for (int r = 0; r < 4; ++r) {
                    int tt = g * 4 + r;
                    UN[w][h][tt][(f * 16 + li) ^ ((tt & 7) << 3)] = f2b(S[f][r]);
                }
        };
        smax(S0, bd0, lrow0, 0);
        smax(S1, bd1, lrow1, 1);
        // PV: vb shared across rowgroups
        __builtin_amdgcn_s_setprio(1);
#pragma unroll
        for (int ks = 0; ks < 2; ++ks) {
            const int colsw = (ks * 32 + g * 8) ^ ((li & 7) << 3);
            bf16x8 pa0 = *reinterpret_cast<const bf16x8*>(&UN[w][0][li][colsw]);
            bf16x8 pa1 = *reinterpret_cast<const bf16x8*>(&UN[w][1][li][colsw]);
#pragma unroll
            for (int fd = 0; fd < 4; ++fd) {
                bf16x8 vb = *reinterpret_cast<const bf16x8*>(&Vs[cur][fd * 16 + li][colsw]);
                O0[fd] = __builtin_amdgcn_mfma_f32_16x16x32_bf16(pa0, vb, O0[fd], 0, 0, 0);
                O1[fd] = __builtin_amdgcn_mfma_f32_16x16x32_bf16(pa1, vb, O1[fd], 0, 0, 0);
            }
        }
        __builtin_amdgcn_s_setprio(0);
        // stage next tile into disjoint regions; single barrier publishes
        if (it < 7) {
#pragma unroll
            for (int i = 0; i < 2; ++i) {
                int row = srow + i * 32;
                *reinterpret_cast<bf16x8*>(&Ks[cur ^ 1][row][scolsw]) = kreg[i];
                *reinterpret_cast<bf16x8*>(&Vs[cur ^ 1][row][scolsw]) = vreg[i];
                *reinterpret_cast<bf16x8*>(&Pw[(base0 + s0 + 192 + row) & 255][scolsw]) = preg[i];
            }
            __syncthreads();
        }
        cur ^= 1;
    }
    // final row-sum reduce across the 16 lanes of each group
#pragma unroll
    for (int r = 0; r < 4; ++r) {
#pragma unroll
        for (int msk = 1; msk < 16; msk <<= 1) {
            lrow0[r] += __shfl_xor(lrow0[r], msk);
            lrow1[r] += __shfl_xor(lrow1[r], msk);
        }
    }
#pragma unroll
    for (int fd = 0; fd < 4; ++fd) {
#pragma unroll
        for (int r = 0; r < 4; ++r) {
            int t_a = t0 + (w * 2) * 16 + g * 4 + r;
            int d = fd * 16 + li;
            out[((long)(bb * 512 + t_a)) * 512 + hh * 64 + d] = O0[fd][r] / lrow0[r];
            out[((long)(bb * 512 + t_a + 16)) * 512 + hh * 64 + d] = O1[fd][r] / lrow1[r];
        }
    }
}

extern "C" void kernel_launch(void* const* d_in, const int* in_sizes, int n_in,
                              void* d_out, int out_size, void* d_ws, size_t ws_size,
                              hipStream_t stream)
{
    const float* x   = (const float*)d_in[0];
    const float* pe  = (const float*)d_in[1];
    const float* Wq  = (const float*)d_in[2];
    const float* bq  = (const float*)d_in[3];
    const float* Wk  = (const float*)d_in[4];
    const float* bk  = (const float*)d_in[5];
    const float* Wv  = (const float*)d_in[6];
    const float* bv  = (const float*)d_in[7];
    const float* Wp  = (const float*)d_in[8];
    const float* pbu = (const float*)d_in[9];
    const float* pbv = (const float*)d_in[10];
    float* out = (float*)d_out;

    unsigned short* qu = (unsigned short*)d_ws;                  // [BH][512][64]
    unsigned short* qv = qu + (size_t)BH_ * 512 * 64;
    unsigned short* kk = qv + (size_t)BH_ * 512 * 64;
    unsigned short* vT = kk + (size_t)BH_ * 512 * 64;            // [BH][64][512]
    unsigned short* p  = vT + (size_t)BH_ * 512 * 64;            // [BH][1024][64]
    unsigned short* xb = p  + (size_t)BH_ * 1024 * 64;           // [8192][512]
    unsigned short* pb = xb + (size_t)NX_;                       // [16*1023][512]
    unsigned short* wb = pb + (size_t)NPE_;                      // [4*512][512]

    dim3 blk(256);
    convert_bf16<<<dim3(6656), blk, 0, stream>>>(x, pe, Wq, Wk, Wv, Wp, xb, pb, wb, p);
    proj_all<<<dim3(1280), blk, 0, stream>>>(xb, pb, wb, bq, bk, bv, pbu, pbv, qu, qv, kk, vT, p);
    attn_fused<<<dim3(512), blk, 0, stream>>>(qu, qv, kk, vT, p, out);
}

// Round 17
// 81.262 us; speedup vs baseline: 1.1937x; 1.1937x over previous
//
#include <hip/hip_runtime.h>
#include <hip/hip_bf16.h>

static constexpr int B_ = 16, T_ = 512, E_ = 512, H_ = 8, HD_ = 64;
static constexpr int S2_ = 1023, BH_ = B_ * H_;

typedef __attribute__((ext_vector_type(4))) float f32x4;
typedef __attribute__((ext_vector_type(8))) short bf16x8;

__device__ __forceinline__ unsigned short f2b(float f) {
    union { float f; unsigned u; } v; v.f = f;
    unsigned r = (v.u + 0x7fff + ((v.u >> 16) & 1)) >> 16;
    return (unsigned short)r;
}
__device__ __forceinline__ unsigned int pk2(float a, float b) {
    __hip_bfloat162 h = __float22bfloat162_rn(float2{a, b});
    union { __hip_bfloat162 h; unsigned int u; } c; c.h = h; return c.u;
}
__device__ __forceinline__ void gll16(const unsigned short* g, unsigned short* l) {
    __builtin_amdgcn_global_load_lds((const __attribute__((address_space(1))) unsigned int*)g,
                                     (__attribute__((address_space(3))) unsigned int*)l, 16, 0, 0);
}

// fp32 -> bf16 convert of x, pos_emb, Wq,Wk,Wv,Wp ; tail blocks zero p row 1023.
static constexpr long NX_ = 4194304;        // 16*512*512
static constexpr long NPE_ = 8380416;       // 16*1023*512
static constexpr long NW_ = 262144;         // 512*512
static constexpr long TOT_ = NX_ + NPE_ + 4 * NW_;   // 13623296
__global__ __launch_bounds__(256)
void convert_bf16(const float* __restrict__ x, const float* __restrict__ pe,
                  const float* __restrict__ wq, const float* __restrict__ wk,
                  const float* __restrict__ wv, const float* __restrict__ wp,
                  unsigned short* __restrict__ xb, unsigned short* __restrict__ pb,
                  unsigned short* __restrict__ wb, unsigned short* __restrict__ p)
{
    long i8 = ((long)blockIdx.x * 256 + threadIdx.x) * 8;
    if (i8 >= TOT_) {
        long idx8 = i8 - TOT_;                 // [0, 8192)
        int bh = (int)(idx8 >> 6), d = (int)(idx8 & 63);
        bf16x8 z = {};
        *reinterpret_cast<bf16x8*>(&p[((long)bh * 1024 + 1023) * 64 + d]) = z;
        return;
    }
    const float* src;
    unsigned short* dst;
    if (i8 < NX_) { src = x + i8; dst = xb + i8; }
    else if (i8 < NX_ + NPE_) { long o = i8 - NX_; src = pe + o; dst = pb + o; }
    else {
        long w = i8 - (NX_ + NPE_);
        int which = (int)(w >> 18);
        long off = w & (NW_ - 1);
        src = (which == 0 ? wq : which == 1 ? wk : which == 2 ? wv : wp) + off;
        dst = wb + ((long)which << 18) + off;
    }
    float4 a = *reinterpret_cast<const float4*>(src);
    float4 b = *reinterpret_cast<const float4*>(src + 4);
    union { bf16x8 v; unsigned int u[4]; } r;
    r.u[0] = pk2(a.x, a.y); r.u[1] = pk2(a.z, a.w);
    r.u[2] = pk2(b.x, b.y); r.u[3] = pk2(b.z, b.w);
    *reinterpret_cast<bf16x8*>(dst) = r.v;
}

// Unified projection GEMM (r10-proven): double-buffered gll16 staging, counted
// vmcnt, XOR-swizzled linear LDS, LDS-staged coalesced bf16x8 epilogue.
// blocks 0..767: QKV (mode 0/1/2), blocks 768..1279: P (mode 3).
// qu/qv carry 0.125*log2(e) so attention softmax can use native exp2.
__global__ __launch_bounds__(256)
void proj_all(const unsigned short* __restrict__ xb, const unsigned short* __restrict__ pb,
              const unsigned short* __restrict__ wb,
              const float* __restrict__ bq, const float* __restrict__ bk,
              const float* __restrict__ bv,
              const float* __restrict__ pbu, const float* __restrict__ pbv,
              unsigned short* __restrict__ qu, unsigned short* __restrict__ qv,
              unsigned short* __restrict__ kk, unsigned short* __restrict__ vT,
              unsigned short* __restrict__ pout)
{
    __shared__ __align__(16) unsigned short LDS[2][2][8192];   // [buf][A/W][128*64]
    const int tid = threadIdx.x;
    const int lane = tid & 63, w = tid >> 6;
    const int wr = w >> 1, wc = w & 1;
    const int g = lane >> 4, li = lane & 15;
    const int lr = lane >> 3;
    const int lcs = (((lane & 7) ^ (lane >> 3)) * 8);   // pre-swizzled source col

    int mode, m0, n0, M;
    const unsigned short* Ap;
    const float* bias = nullptr;
    if (blockIdx.x < 768) {
        int n = blockIdx.x;
        int xcd = n & 7, s = n >> 3;
        int gi = s / 12, c = s % 12;
        m0 = (gi * 8 + xcd) * 128;
        mode = c >> 2; n0 = (c & 3) * 128;
        Ap = xb; M = 8192;
        bias = (mode == 0) ? bq : (mode == 1) ? bk : bv;
    } else {
        int n = blockIdx.x - 768;
        int xcd = n & 7, s = n >> 3;
        int gi = s >> 2, c = s & 3;
        m0 = (gi * 8 + xcd) * 128;
        mode = 3; n0 = c * 128;
        Ap = pb; M = B_ * S2_;
    }
    const unsigned short* W = wb + ((long)mode << 18);

    auto stage = [&](int buf, int k0) {
#pragma unroll
        for (int i = 0; i < 4; ++i) {
            int c = w * 4 + i;
            int ar = m0 + c * 8 + lr; if (ar > M - 1) ar = M - 1;
            gll16(&Ap[(long)ar * 512 + k0 + lcs], &LDS[buf][0][c * 512]);
            gll16(&W[(long)(n0 + c * 8 + lr) * 512 + k0 + lcs], &LDS[buf][1][c * 512]);
        }
    };

    f32x4 acc[4][4] = {};
    stage(0, 0);
    for (int s = 0; s < 8; ++s) {
        if (s < 7) stage((s + 1) & 1, (s + 1) * 64);
        __builtin_amdgcn_sched_barrier(0);
        if (s < 7) { asm volatile("s_waitcnt vmcnt(8)" ::: "memory"); }
        else       { asm volatile("s_waitcnt vmcnt(0)" ::: "memory"); }
        __builtin_amdgcn_sched_barrier(0);
        __builtin_amdgcn_s_barrier();
        __builtin_amdgcn_sched_barrier(0);   // ds_reads must stay AFTER the barrier
        const unsigned short* As = &LDS[s & 1][0][0];
        const unsigned short* Ws = &LDS[s & 1][1][0];
#pragma unroll
        for (int ks = 0; ks < 2; ++ks) {
            bf16x8 a[4], b[4];
            const int colsw = (ks * 32 + g * 8) ^ ((li & 7) << 3);
#pragma unroll
            for (int m = 0; m < 4; ++m)
                a[m] = *reinterpret_cast<const bf16x8*>(&As[(wr * 64 + m * 16 + li) * 64 + colsw]);
#pragma unroll
            for (int nn = 0; nn < 4; ++nn)
                b[nn] = *reinterpret_cast<const bf16x8*>(&Ws[(wc * 64 + nn * 16 + li) * 64 + colsw]);
            __builtin_amdgcn_s_setprio(1);
#pragma unroll
            for (int m = 0; m < 4; ++m)
#pragma unroll
                for (int nn = 0; nn < 4; ++nn)
                    acc[m][nn] = __builtin_amdgcn_mfma_f32_16x16x32_bf16(a[m], b[nn], acc[m][nn], 0, 0, 0);
            __builtin_amdgcn_s_setprio(0);
        }
        __builtin_amdgcn_sched_barrier(0);
        __builtin_amdgcn_s_barrier();
        __builtin_amdgcn_sched_barrier(0);
    }

    // Epilogue scalars (after vmcnt(0); compiler-managed waits)
    float bias_[4] = {0.f, 0.f, 0.f, 0.f}, pu_[4] = {0.f, 0.f, 0.f, 0.f}, pv_[4] = {0.f, 0.f, 0.f, 0.f};
    if (mode != 3) {
#pragma unroll
        for (int nn = 0; nn < 4; ++nn) {
            int gn = n0 + wc * 64 + nn * 16 + li;
            bias_[nn] = bias[gn];
            if (mode == 0) { pu_[nn] = pbu[gn]; pv_[nn] = pbv[gn]; }
        }
    }

    // ---- LDS-staged coalesced epilogue: Ct is a [128][136] bf16 tile ----
    unsigned short* Ct = &LDS[0][0][0];
    const int rrow = tid >> 4, rcol = (tid & 15) * 8;
    const float QS = 0.125f * 1.4426950408889634f;   // 1/8 * log2(e)

    if (mode == 2) {
#pragma unroll
        for (int m = 0; m < 4; ++m)
#pragma unroll
            for (int nn = 0; nn < 4; ++nn) {
                ushort4 pk;
                pk.x = f2b(acc[m][nn][0] + bias_[nn]);
                pk.y = f2b(acc[m][nn][1] + bias_[nn]);
                pk.z = f2b(acc[m][nn][2] + bias_[nn]);
                pk.w = f2b(acc[m][nn][3] + bias_[nn]);
                *reinterpret_cast<ushort4*>(&Ct[(wc * 64 + nn * 16 + li) * 136 + wr * 64 + m * 16 + g * 4]) = pk;
            }
        __syncthreads();
#pragma unroll
        for (int ps = 0; ps < 8; ++ps) {
            int rowd = ps * 16 + rrow;
            int gn = n0 + rowd, gm = m0 + rcol;
            int hh = gn >> 6, d = gn & 63, bb = gm >> 9, t = gm & 511;
            *reinterpret_cast<bf16x8*>(&vT[((long)(bb * 8 + hh) * 64 + d) * 512 + t]) =
                *reinterpret_cast<const bf16x8*>(&Ct[rowd * 136 + rcol]);
        }
    } else if (mode != 0) {
#pragma unroll
        for (int m = 0; m < 4; ++m)
#pragma unroll
            for (int nn = 0; nn < 4; ++nn)
#pragma unroll
                for (int r = 0; r < 4; ++r)
                    Ct[(wr * 64 + m * 16 + g * 4 + r) * 136 + wc * 64 + nn * 16 + li] =
                        f2b(acc[m][nn][r] + bias_[nn]);
        __syncthreads();
#pragma unroll
        for (int ps = 0; ps < 8; ++ps) {
            int row = ps * 16 + rrow;
            int gm = m0 + row, gn = n0 + rcol;
            bf16x8 v = *reinterpret_cast<const bf16x8*>(&Ct[row * 136 + rcol]);
            if (mode == 1) {
                int bb = gm >> 9, t = gm & 511, hh = gn >> 6, d = gn & 63;
                *reinterpret_cast<bf16x8*>(&kk[((long)(bb * 8 + hh) * 512 + t) * 64 + d]) = v;
            } else if (gm < M) {
                int bb = gm / 1023, j = gm - bb * 1023;
                int hh = gn >> 6, d = gn & 63;
                *reinterpret_cast<bf16x8*>(&pout[((long)(bb * 8 + hh) * 1024 + j) * 64 + d]) = v;
            }
        }
    } else {
#pragma unroll
        for (int m = 0; m < 4; ++m)
#pragma unroll
            for (int nn = 0; nn < 4; ++nn)
#pragma unroll
                for (int r = 0; r < 4; ++r)
                    Ct[(wr * 64 + m * 16 + g * 4 + r) * 136 + wc * 64 + nn * 16 + li] =
                        f2b((acc[m][nn][r] + bias_[nn] + pu_[nn]) * QS);
        __syncthreads();
#pragma unroll
        for (int ps = 0; ps < 8; ++ps) {
            int row = ps * 16 + rrow;
            int gm = m0 + row, gn = n0 + rcol;
            int bb = gm >> 9, t = gm & 511, hh = gn >> 6, d = gn & 63;
            *reinterpret_cast<bf16x8*>(&qu[((long)(bb * 8 + hh) * 512 + t) * 64 + d]) =
                *reinterpret_cast<const bf16x8*>(&Ct[row * 136 + rcol]);
        }
        __syncthreads();
#pragma unroll
        for (int m = 0; m < 4; ++m)
#pragma unroll
            for (int nn = 0; nn < 4; ++nn)
#pragma unroll
                for (int r = 0; r < 4; ++r)
                    Ct[(wr * 64 + m * 16 + g * 4 + r) * 136 + wc * 64 + nn * 16 + li] =
                        f2b((acc[m][nn][r] + bias_[nn] + pv_[nn]) * QS);
        __syncthreads();
#pragma unroll
        for (int ps = 0; ps < 8; ++ps) {
            int row = ps * 16 + rrow;
            int gm = m0 + row, gn = n0 + rcol;
            int bb = gm >> 9, t = gm & 511, hh = gn >> 6, d = gn & 63;
            *reinterpret_cast<bf16x8*>(&qv[((long)(bb * 8 + hh) * 512 + t) * 64 + d]) =
                *reinterpret_cast<const bf16x8*>(&Ct[row * 136 + rcol]);
        }
    }
}

// Fused attention v7 (r15 best): QBLK=128, 8 waves; double-buffered K/V +
// 256-row circular Pw (64 new rows/tile), ONE barrier per tile. In-register
// shfl diagonal gather, exp2 softmax, no-max, deferred sum.
__global__ __launch_bounds__(512)
void attn_fused(const unsigned short* __restrict__ qu, const unsigned short* __restrict__ qv,
                const unsigned short* __restrict__ kk, const unsigned short* __restrict__ vT,
                const unsigned short* __restrict__ p, float* __restrict__ out)
{
    __shared__ unsigned short Ks[2][64][64];   // XOR-swizzled: col ^ ((row&7)<<3)
    __shared__ unsigned short Vs[2][64][64];
    __shared__ unsigned short Pw[256][64];     // circular window, row = global&255
    __shared__ unsigned short UN[8][16][64];   // per-wave P strip, swizzled
    const int tid = threadIdx.x, lane = tid & 63, w = tid >> 6;   // w 0..7
    const int g = lane >> 4, li = lane & 15;
    const int n = blockIdx.x;            // 0..511, XCD-swizzled
    const int xcd = n & 7, rr = n >> 3;
    const int j = rr & 15, ti = rr >> 4; // ti 0..3
    const int bh = xcd * 16 + j;
    const int bb = bh >> 3, hh = bh & 7;
    const int t0 = ti * 128;
    const int wo = 112 - w * 16;         // wave's offset into the 192-row window
    const int base0 = 384 - t0;          // p-window base row for s0=0 (>=0)

    bf16x8 aq[2], av[2];
    const int trow = t0 + w * 16 + li;
#pragma unroll
    for (int ks = 0; ks < 2; ++ks) {
        aq[ks] = *reinterpret_cast<const bf16x8*>(&qu[((long)bh * 512 + trow) * 64 + ks * 32 + g * 8]);
        av[ks] = *reinterpret_cast<const bf16x8*>(&qv[((long)bh * 512 + trow) * 64 + ks * 32 + g * 8]);
    }

    const int srow = tid >> 3, scol8 = (tid & 7) * 8;    // 512 thr -> 64 rows x 64 cols
    const int scolsw = scol8 ^ ((srow & 7) << 3);        // swizzled LDS col

    // prologue: tile-0 K/V and the initial 192-row p window
    {
        bf16x8 k0 = *reinterpret_cast<const bf16x8*>(&kk[((long)bh * 512 + srow) * 64 + scol8]);
        bf16x8 v0 = *reinterpret_cast<const bf16x8*>(&vT[((long)bh * 64 + srow) * 512 + scol8]);
        *reinterpret_cast<bf16x8*>(&Ks[0][srow][scolsw]) = k0;
        *reinterpret_cast<bf16x8*>(&Vs[0][srow][scolsw]) = v0;
#pragma unroll
        for (int i = 0; i < 3; ++i) {
            int pr = base0 + srow + i * 64;
            bf16x8 pv = *reinterpret_cast<const bf16x8*>(&p[((long)bh * 1024 + pr) * 64 + scol8]);
            *reinterpret_cast<bf16x8*>(&Pw[pr & 255][scolsw]) = pv;
        }
    }
    __syncthreads();

    f32x4 O[4] = {};
    float lrow[4] = {0.f, 0.f, 0.f, 0.f};
    bf16x8 kreg, vreg, preg;
    int cur = 0;

    for (int it = 0; it < 8; ++it) {
        const int s0 = it * 64;
        if (it < 7) {      // issue next-tile loads early (hide under compute)
            kreg = *reinterpret_cast<const bf16x8*>(&kk[((long)bh * 512 + s0 + 64 + srow) * 64 + scol8]);
            vreg = *reinterpret_cast<const bf16x8*>(&vT[((long)bh * 64 + srow) * 512 + s0 + 64 + scol8]);
            preg = *reinterpret_cast<const bf16x8*>(&p[((long)bh * 1024 + base0 + s0 + 192 + srow) * 64 + scol8]);
        }
        // QK^T + BD (B-fragments from swizzled LDS)
        f32x4 S[4] = {};
        f32x4 bd[5] = {};
        __builtin_amdgcn_s_setprio(1);
#pragma unroll
        for (int ks = 0; ks < 2; ++ks) {
            const int colsw = (ks * 32 + g * 8) ^ ((li & 7) << 3);
#pragma unroll
            for (int f = 0; f < 4; ++f) {
                bf16x8 bf = *reinterpret_cast<const bf16x8*>(&Ks[cur][f * 16 + li][colsw]);
                S[f] = __builtin_amdgcn_mfma_f32_16x16x32_bf16(aq[ks], bf, S[f], 0, 0, 0);
            }
#pragma unroll
            for (int fb = 0; fb < 5; ++fb) {
                int prow = (base0 + s0 + wo + fb * 16 + li) & 255;
                bf16x8 bf = *reinterpret_cast<const bf16x8*>(&Pw[prow][colsw]);
                bd[fb] = __builtin_amdgcn_mfma_f32_16x16x32_bf16(av[ks], bf, bd[fb], 0, 0, 0);
            }
        }
        __builtin_amdgcn_s_setprio(0);
        // diagonal rel-shift gather in-register: S[t,s] += BD[t, s-t+15]
#pragma unroll
        for (int r = 0; r < 4; ++r) {
            const int tt = g * 4 + r;
            const int sh = 15 - tt;
            const int srcl = (lane & 48) | ((li + sh) & 15);
            const bool wrap = (li + sh) >= 16;
            float sv[5];
#pragma unroll
            for (int q = 0; q < 5; ++q) sv[q] = __shfl(bd[q][r], srcl, 64);
#pragma unroll
            for (int f = 0; f < 4; ++f) {
                float pv = __builtin_exp2f(S[f][r] + (wrap ? sv[f + 1] : sv[f]));
                S[f][r] = pv;
                lrow[r] += pv;
            }
        }
        // P -> per-wave LDS strip (swizzled transpose to A-fragment layout)
#pragma unroll
        for (int f = 0; f < 4; ++f)
#pragma unroll
            for (int r = 0; r < 4; ++r) {
                int tt = g * 4 + r;
                UN[w][tt][(f * 16 + li) ^ ((tt & 7) << 3)] = f2b(S[f][r]);
            }
        // PV
        __builtin_amdgcn_s_setprio(1);
#pragma unroll
        for (int ks = 0; ks < 2; ++ks) {
            const int colsw = (ks * 32 + g * 8) ^ ((li & 7) << 3);
            bf16x8 pa = *reinterpret_cast<const bf16x8*>(&UN[w][li][colsw]);
#pragma unroll
            for (int fd = 0; fd < 4; ++fd) {
                bf16x8 vb = *reinterpret_cast<const bf16x8*>(&Vs[cur][fd * 16 + li][colsw]);
                O[fd] = __builtin_amdgcn_mfma_f32_16x16x32_bf16(pa, vb, O[fd], 0, 0, 0);
            }
        }
        __builtin_amdgcn_s_setprio(0);
        // stage next tile into DISJOINT regions; single barrier publishes.
        if (it < 7) {
            *reinterpret_cast<bf16x8*>(&Ks[cur ^ 1][srow][scolsw]) = kreg;
            *reinterpret_cast<bf16x8*>(&Vs[cur ^ 1][srow][scolsw]) = vreg;
            *reinterpret_cast<bf16x8*>(&Pw[(base0 + s0 + 192 + srow) & 255][scolsw]) = preg;
            __syncthreads();
        }
        cur ^= 1;
    }
    // final row-sum reduce across the 16 lanes of each group
#pragma unroll
    for (int r = 0; r < 4; ++r) {
#pragma unroll
        for (int msk = 1; msk < 16; msk <<= 1)
            lrow[r] += __shfl_xor(lrow[r], msk);
        lrow[r] = 1.0f / lrow[r];
    }
#pragma unroll
    for (int fd = 0; fd < 4; ++fd) {
#pragma unroll
        for (int r = 0; r < 4; ++r) {
            int t = t0 + w * 16 + g * 4 + r;
            int d = fd * 16 + li;
            out[((long)(bb * 512 + t)) * 512 + hh * 64 + d] = O[fd][r] * lrow[r];
        }
    }
}

extern "C" void kernel_launch(void* const* d_in, const int* in_sizes, int n_in,
                              void* d_out, int out_size, void* d_ws, size_t ws_size,
                              hipStream_t stream)
{
    const float* x   = (const float*)d_in[0];
    const float* pe  = (const float*)d_in[1];
    const float* Wq  = (const float*)d_in[2];
    const float* bq  = (const float*)d_in[3];
    const float* Wk  = (const float*)d_in[4];
    const float* bk  = (const float*)d_in[5];
    const float* Wv  = (const float*)d_in[6];
    const float* bv  = (const float*)d_in[7];
    const float* Wp  = (const float*)d_in[8];
    const float* pbu = (const float*)d_in[9];
    const float* pbv = (const float*)d_in[10];
    float* out = (float*)d_out;

    unsigned short* qu = (unsigned short*)d_ws;                  // [BH][512][64]
    unsigned short* qv = qu + (size_t)BH_ * 512 * 64;
    unsigned short* kk = qv + (size_t)BH_ * 512 * 64;
    unsigned short* vT = kk + (size_t)BH_ * 512 * 64;            // [BH][64][512]
    unsigned short* p  = vT + (size_t)BH_ * 512 * 64;            // [BH][1024][64]
    unsigned short* xb = p  + (size_t)BH_ * 1024 * 64;           // [8192][512]
    unsigned short* pb = xb + (size_t)NX_;                       // [16*1023][512]
    unsigned short* wb = pb + (size_t)NPE_;                      // [4*512][512]

    dim3 blk(256);
    convert_bf16<<<dim3(6656), blk, 0, stream>>>(x, pe, Wq, Wk, Wv, Wp, xb, pb, wb, p);
    proj_all<<<dim3(1280), blk, 0, stream>>>(xb, pb, wb, bq, bk, bv, pbu, pbv, qu, qv, kk, vT, p);
    attn_fused<<<dim3(512), dim3(512), 0, stream>>>(qu, qv, kk, vT, p, out);
}